// Round 2
// baseline (3588.035 us; speedup 1.0000x reference)
//
#include <hip/hip_runtime.h>
#include <hip/hip_cooperative_groups.h>

namespace cg = cooperative_groups;

#define N 8192
#define EPS 1e-8f

// ---- bf16 helpers (manual, positive finite values only) ----
__device__ __forceinline__ unsigned short f2bf(float f) {
    // round-to-nearest-even
    unsigned int u = __float_as_uint(f);
    unsigned int rounding = 0x7FFFu + ((u >> 16) & 1u);
    return (unsigned short)((u + rounding) >> 16);
}
__device__ __forceinline__ float bflo(unsigned int w) { return __uint_as_float(w << 16); }
__device__ __forceinline__ float bfhi(unsigned int w) { return __uint_as_float(w & 0xffff0000u); }
__device__ __forceinline__ unsigned int pack2(unsigned short lo, unsigned short hi) {
    return (unsigned int)lo | ((unsigned int)hi << 16);
}

// dot of 8 packed bf16 (uint4) with 8 floats (two float4)
__device__ __forceinline__ float dot8(uint4 kv, float4 xa, float4 xb) {
    float a = 0.f;
    a = fmaf(bflo(kv.x), xa.x, a);
    a = fmaf(bfhi(kv.x), xa.y, a);
    a = fmaf(bflo(kv.y), xa.z, a);
    a = fmaf(bfhi(kv.y), xa.w, a);
    a = fmaf(bflo(kv.z), xb.x, a);
    a = fmaf(bfhi(kv.z), xb.y, a);
    a = fmaf(bflo(kv.w), xb.z, a);
    a = fmaf(bfhi(kv.w), xb.w, a);
    return a;
}

// ---- init raw-v accumulator: buf0[j] = N  (so rcp(buf0+eps) = 1/N) ----
__global__ __launch_bounds__(256) void init_vacc_kernel(float* __restrict__ b0) {
    int i = blockIdx.x * 256 + threadIdx.x;
    if (i < N) b0[i] = (float)N;
}

// ---- build K (bf16, row-major) from s, m. Pure elementwise, 8 elems/thread ----
__global__ __launch_bounds__(256) void build_K_kernel(
    const float* __restrict__ s, const float* __restrict__ m,
    unsigned short* __restrict__ K) {
    const size_t base = ((size_t)blockIdx.x * 256 + threadIdx.x) * 8;
    const float4 sa = *(const float4*)(s + base);
    const float4 sb = *(const float4*)(s + base + 4);
    const float4 ma = *(const float4*)(m + base);
    const float4 mb = *(const float4*)(m + base + 4);
    uint4 pk;
    pk.x = pack2(f2bf(__expf(sa.x) * ma.x), f2bf(__expf(sa.y) * ma.y));
    pk.y = pack2(f2bf(__expf(sa.z) * ma.z), f2bf(__expf(sa.w) * ma.w));
    pk.z = pack2(f2bf(__expf(sb.x) * mb.x), f2bf(__expf(sb.y) * mb.y));
    pk.w = pack2(f2bf(__expf(sb.z) * mb.z), f2bf(__expf(sb.w) * mb.w));
    *(uint4*)(K + base) = pk;
}

// ---- persistent cooperative kernel: all 20 Sinkhorn iterations ----
// Phase A (u-update): block g handles rows g*8..g*8+7:
//   u[i] = 1/(eps + sum_j K[i,j] * rcp(vaccR[j]+eps));  also zeroes vaccW slice.
// Phase B (v-update): tile t: colstripe (t&127)*64, rowchunk (t>>7)*1024;
//   partial col sums of K^T * u  atomically added into vaccW.
// Ping-pong vaccR/vaccW; 2 grid syncs per iteration.
__global__ __launch_bounds__(256, 4) void sinkhorn_iter_kernel(
    const unsigned short* __restrict__ K,
    float* __restrict__ u,
    float* __restrict__ buf0, float* __restrict__ buf1,
    float* __restrict__ vhat) {
    cg::grid_group grid = cg::this_grid();
    const int tid = threadIdx.x;
    const int bid = blockIdx.x;
    const int nb = gridDim.x;

    __shared__ float su[1024];
    __shared__ float wredB[32][64];
    __shared__ float wredA[8][4];

    for (int t = 0; t < 20; ++t) {
        float* __restrict__ vaccR = (t & 1) ? buf1 : buf0;
        float* __restrict__ vaccW = (t & 1) ? buf0 : buf1;

        // ---------------- Phase A: u-update ----------------
        for (int g = bid; g < N / 8; g += nb) {
            const int rowBase = g * 8;
            float acc[8];
            #pragma unroll
            for (int r = 0; r < 8; ++r) acc[r] = 0.f;

            #pragma unroll
            for (int sweep = 0; sweep < 4; ++sweep) {
                const int col = sweep * 2048 + tid * 8;
                float4 xa = *(const float4*)(vaccR + col);
                float4 xb = *(const float4*)(vaccR + col + 4);
                xa.x = __builtin_amdgcn_rcpf(xa.x + EPS);
                xa.y = __builtin_amdgcn_rcpf(xa.y + EPS);
                xa.z = __builtin_amdgcn_rcpf(xa.z + EPS);
                xa.w = __builtin_amdgcn_rcpf(xa.w + EPS);
                xb.x = __builtin_amdgcn_rcpf(xb.x + EPS);
                xb.y = __builtin_amdgcn_rcpf(xb.y + EPS);
                xb.z = __builtin_amdgcn_rcpf(xb.z + EPS);
                xb.w = __builtin_amdgcn_rcpf(xb.w + EPS);
                #pragma unroll
                for (int r = 0; r < 8; ++r) {
                    const uint4 kv = *(const uint4*)(K + (size_t)(rowBase + r) * N + col);
                    acc[r] += dot8(kv, xa, xb);
                }
            }

            const int lane = tid & 63;
            const int wave = tid >> 6;
            #pragma unroll
            for (int r = 0; r < 8; ++r) {
                float a = acc[r];
                #pragma unroll
                for (int off = 32; off > 0; off >>= 1) a += __shfl_down(a, off, 64);
                if (lane == 0) wredA[r][wave] = a;
            }
            __syncthreads();
            if (tid < 8) {
                const float ssum = wredA[tid][0] + wredA[tid][1] + wredA[tid][2] + wredA[tid][3];
                u[rowBase + tid] = 1.0f / (ssum + EPS);   // precise: defines u exactly
                vaccW[rowBase + tid] = 0.f;               // zero next accumulator
            }
            __syncthreads();
        }
        grid.sync();

        // ---------------- Phase B: v-update (K^T * u, atomic col sums) ----------------
        for (int tile = bid; tile < 1024; tile += nb) {
            const int colBase = (tile & 127) * 64;
            const int rowBase = (tile >> 7) * 1024;

            // stage the u chunk (already reciprocal'd) into LDS
            *(float4*)(su + tid * 4) = *(const float4*)(u + rowBase + tid * 4);
            __syncthreads();

            const int rg = tid >> 3;   // 0..31 (row group)
            const int cl = tid & 7;    // 0..7  (8 cols of 8 each = 64 cols)
            float acc[8];
            #pragma unroll
            for (int r = 0; r < 8; ++r) acc[r] = 0.f;

            const unsigned short* Kp = K + (size_t)(rowBase + rg) * N + colBase + cl * 8;
            #pragma unroll 4
            for (int step = 0; step < 32; ++step) {
                const uint4 w = *(const uint4*)(Kp + (size_t)step * 32 * N);
                const float uv = su[step * 32 + rg];
                acc[0] = fmaf(bflo(w.x), uv, acc[0]);
                acc[1] = fmaf(bfhi(w.x), uv, acc[1]);
                acc[2] = fmaf(bflo(w.y), uv, acc[2]);
                acc[3] = fmaf(bfhi(w.y), uv, acc[3]);
                acc[4] = fmaf(bflo(w.z), uv, acc[4]);
                acc[5] = fmaf(bfhi(w.z), uv, acc[5]);
                acc[6] = fmaf(bflo(w.w), uv, acc[6]);
                acc[7] = fmaf(bfhi(w.w), uv, acc[7]);
            }

            *(float4*)&wredB[rg][cl * 8]     = make_float4(acc[0], acc[1], acc[2], acc[3]);
            *(float4*)&wredB[rg][cl * 8 + 4] = make_float4(acc[4], acc[5], acc[6], acc[7]);
            __syncthreads();
            if (tid < 64) {
                float ssum = 0.f;
                #pragma unroll
                for (int g2 = 0; g2 < 32; ++g2) ssum += wredB[g2][tid];
                atomicAdd(&vaccW[colBase + tid], ssum);
            }
            __syncthreads();
        }
        grid.sync();
    }

    // epilogue: final raw v is in buf0 (t=19 wrote vaccW=buf0); vhat = 1/(buf0+eps)
    for (int g = bid; g < N / 256; g += nb) {
        const int j = g * 256 + tid;
        vhat[j] = 1.0f / (buf0[j] + EPS);
    }
}

// ---- final: out[i][j] = u[i] * exp(s[i][j]) * m[i][j] * v[j] (fp32 exact K) ----
__global__ __launch_bounds__(256) void final_kernel(
    const float* __restrict__ s, const float* __restrict__ m,
    const float* __restrict__ u, const float* __restrict__ v,
    float* __restrict__ out) {
    const int row = blockIdx.x;
    const float ur = u[row];
    const int tid = threadIdx.x;
    #pragma unroll
    for (int sweep = 0; sweep < 8; ++sweep) {
        const int col = sweep * 1024 + tid * 4;
        const size_t idx = (size_t)row * N + col;
        const float4 s4 = *(const float4*)(s + idx);
        const float4 m4 = *(const float4*)(m + idx);
        const float4 v4 = *(const float4*)(v + col);
        float4 o;
        o.x = ur * __expf(s4.x) * m4.x * v4.x;
        o.y = ur * __expf(s4.y) * m4.y * v4.y;
        o.z = ur * __expf(s4.z) * m4.z * v4.z;
        o.w = ur * __expf(s4.w) * m4.w * v4.w;
        *(float4*)(out + idx) = o;
    }
}

extern "C" void kernel_launch(void* const* d_in, const int* in_sizes, int n_in,
                              void* d_out, int out_size, void* d_ws, size_t ws_size,
                              hipStream_t stream) {
    const float* eta = (const float*)d_in[0];
    const float* s = eta;                       // eta_result[0]: scores
    const float* m = eta + (size_t)N * N;       // eta_result[1]: mask
    float* out = (float*)d_out;

    // workspace: K bf16 (128 MiB) | buf0 | buf1 | u | vhat (32 KiB each)
    unsigned short* K = (unsigned short*)d_ws;
    float* buf0 = (float*)(K + (size_t)N * N);
    float* buf1 = buf0 + N;
    float* u    = buf1 + N;
    float* vhat = u + N;

    init_vacc_kernel<<<N / 256, 256, 0, stream>>>(buf0);
    build_K_kernel<<<(int)(((size_t)N * N) / 2048), 256, 0, stream>>>(s, m, K);

    // cooperative persistent kernel: grid sized to guaranteed co-residency
    int maxBlocksPerCU = 0;
    hipOccupancyMaxActiveBlocksPerMultiprocessor(&maxBlocksPerCU, sinkhorn_iter_kernel, 256, 0);
    if (maxBlocksPerCU < 1) maxBlocksPerCU = 1;
    int grid = maxBlocksPerCU * 256;   // 256 CUs on MI355X
    if (grid > 1024) grid = 1024;      // 1024 logical tiles; extra blocks would idle

    void* args[] = { (void*)&K, (void*)&u, (void*)&buf0, (void*)&buf1, (void*)&vhat };
    hipLaunchCooperativeKernel((void*)sinkhorn_iter_kernel, dim3(grid), dim3(256),
                               args, 0, stream);

    final_kernel<<<N, 256, 0, stream>>>(s, m, u, vhat, out);
}

// Round 3
// 3277.454 us; speedup vs baseline: 1.0948x; 1.0948x over previous
//
#include <hip/hip_runtime.h>

#define N 8192
#define EPS 1e-8f
#define CHUNKS 512   // number of row-chunks = fused-kernel grid (16 rows each)

// ---- bf16 helpers (manual, positive finite values only) ----
__device__ __forceinline__ unsigned short f2bf(float f) {
    // round-to-nearest-even
    unsigned int u = __float_as_uint(f);
    unsigned int rounding = 0x7FFFu + ((u >> 16) & 1u);
    return (unsigned short)((u + rounding) >> 16);
}
__device__ __forceinline__ float bflo(unsigned int w) { return __uint_as_float(w << 16); }
__device__ __forceinline__ float bfhi(unsigned int w) { return __uint_as_float(w & 0xffff0000u); }
__device__ __forceinline__ unsigned int pack2(unsigned short lo, unsigned short hi) {
    return (unsigned int)lo | ((unsigned int)hi << 16);
}

// ---- init x = 1/N (x holds the current v vector) ----
__global__ __launch_bounds__(256) void init_x_kernel(float* __restrict__ x) {
    int i = blockIdx.x * 256 + threadIdx.x;
    if (i < N) x[i] = 1.0f / (float)N;
}

// ---- build K (bf16, row-major) from s, m. Pure elementwise, 8 elems/thread ----
__global__ __launch_bounds__(256) void build_K_kernel(
    const float* __restrict__ s, const float* __restrict__ m,
    unsigned short* __restrict__ K) {
    const size_t base = ((size_t)blockIdx.x * 256 + threadIdx.x) * 8;
    const float4 sa = *(const float4*)(s + base);
    const float4 sb = *(const float4*)(s + base + 4);
    const float4 ma = *(const float4*)(m + base);
    const float4 mb = *(const float4*)(m + base + 4);
    uint4 pk;
    pk.x = pack2(f2bf(__expf(sa.x) * ma.x), f2bf(__expf(sa.y) * ma.y));
    pk.y = pack2(f2bf(__expf(sa.z) * ma.z), f2bf(__expf(sa.w) * ma.w));
    pk.z = pack2(f2bf(__expf(sb.x) * mb.x), f2bf(__expf(sb.y) * mb.y));
    pk.w = pack2(f2bf(__expf(sb.z) * mb.z), f2bf(__expf(sb.w) * mb.w));
    *(uint4*)(K + base) = pk;
}

// ---- fused iteration: ONE pass over K computes u-update AND v-partials ----
// Block owns rows [bid*16, bid*16+16) in 2 stripes of 8; thread t owns cols
// {g*2048 + t*8 .. +8} for g=0..3 (32 cols). K stripe register-resident:
//   pass 1: acc[r] = K[r,:]·x  -> block reduce -> u[r] = 1/(acc+eps)
//   pass 2: colacc[c] += K[r,c]*u[r] (reuses the SAME registers, no re-read)
// Writes one fp32 partial row per block: partial[bid][0..N).
__global__ __launch_bounds__(256, 2) void fused_iter_kernel(
    const unsigned short* __restrict__ K, const float* __restrict__ x,
    float* __restrict__ u, float* __restrict__ partial) {
    const int tid = threadIdx.x;
    const int bid = blockIdx.x;

    __shared__ float wred[8][4];
    __shared__ float su[8];

    // load this thread's 32 x-values (4 groups of 8 contiguous cols)
    float xs[4][8];
    #pragma unroll
    for (int g = 0; g < 4; ++g) {
        const float4 a = *(const float4*)(x + g * 2048 + tid * 8);
        const float4 b = *(const float4*)(x + g * 2048 + tid * 8 + 4);
        xs[g][0] = a.x; xs[g][1] = a.y; xs[g][2] = a.z; xs[g][3] = a.w;
        xs[g][4] = b.x; xs[g][5] = b.y; xs[g][6] = b.z; xs[g][7] = b.w;
    }

    float colacc[4][8];
    #pragma unroll
    for (int g = 0; g < 4; ++g)
        #pragma unroll
        for (int c = 0; c < 8; ++c) colacc[g][c] = 0.f;

    #pragma unroll
    for (int s = 0; s < 2; ++s) {
        const int rowBase = bid * 16 + s * 8;

        // 32 independent 16B loads: K stripe -> registers (32 KB in flight/wave)
        uint4 kr[8][4];
        #pragma unroll
        for (int r = 0; r < 8; ++r)
            #pragma unroll
            for (int g = 0; g < 4; ++g)
                kr[r][g] = *(const uint4*)(K + (size_t)(rowBase + r) * N + g * 2048 + tid * 8);

        // pass 1: row dots
        float acc[8];
        #pragma unroll
        for (int r = 0; r < 8; ++r) {
            float a = 0.f;
            #pragma unroll
            for (int g = 0; g < 4; ++g) {
                a = fmaf(bflo(kr[r][g].x), xs[g][0], a);
                a = fmaf(bfhi(kr[r][g].x), xs[g][1], a);
                a = fmaf(bflo(kr[r][g].y), xs[g][2], a);
                a = fmaf(bfhi(kr[r][g].y), xs[g][3], a);
                a = fmaf(bflo(kr[r][g].z), xs[g][4], a);
                a = fmaf(bfhi(kr[r][g].z), xs[g][5], a);
                a = fmaf(bflo(kr[r][g].w), xs[g][6], a);
                a = fmaf(bfhi(kr[r][g].w), xs[g][7], a);
            }
            acc[r] = a;
        }

        // block reduce 8 row sums across 4 waves
        const int lane = tid & 63;
        const int wave = tid >> 6;
        #pragma unroll
        for (int r = 0; r < 8; ++r) {
            float a = acc[r];
            #pragma unroll
            for (int off = 32; off > 0; off >>= 1) a += __shfl_down(a, off, 64);
            if (lane == 0) wred[r][wave] = a;
        }
        __syncthreads();
        if (tid < 8) {
            const float ssum = wred[tid][0] + wred[tid][1] + wred[tid][2] + wred[tid][3];
            const float ur = 1.0f / (ssum + EPS);   // exact divide: defines u
            u[rowBase + tid] = ur;
            su[tid] = ur;
        }
        __syncthreads();

        // pass 2: column partials from the register-resident stripe
        #pragma unroll
        for (int r = 0; r < 8; ++r) {
            const float ur = su[r];
            #pragma unroll
            for (int g = 0; g < 4; ++g) {
                colacc[g][0] = fmaf(bflo(kr[r][g].x), ur, colacc[g][0]);
                colacc[g][1] = fmaf(bfhi(kr[r][g].x), ur, colacc[g][1]);
                colacc[g][2] = fmaf(bflo(kr[r][g].y), ur, colacc[g][2]);
                colacc[g][3] = fmaf(bfhi(kr[r][g].y), ur, colacc[g][3]);
                colacc[g][4] = fmaf(bflo(kr[r][g].z), ur, colacc[g][4]);
                colacc[g][5] = fmaf(bfhi(kr[r][g].z), ur, colacc[g][5]);
                colacc[g][6] = fmaf(bflo(kr[r][g].w), ur, colacc[g][6]);
                colacc[g][7] = fmaf(bfhi(kr[r][g].w), ur, colacc[g][7]);
            }
        }
        // NOTE: no trailing barrier needed — next stripe's wred write is
        // followed by a __syncthreads() before su is overwritten.
    }

    // write this block's column-partial row (fully coalesced float4 stores)
    float* pp = partial + (size_t)bid * N;
    #pragma unroll
    for (int g = 0; g < 4; ++g) {
        *(float4*)(pp + g * 2048 + tid * 8) =
            make_float4(colacc[g][0], colacc[g][1], colacc[g][2], colacc[g][3]);
        *(float4*)(pp + g * 2048 + tid * 8 + 4) =
            make_float4(colacc[g][4], colacc[g][5], colacc[g][6], colacc[g][7]);
    }
}

// ---- prep: x[j] = 1/(sum_chunk partial[chunk][j] + eps) ----
__global__ __launch_bounds__(256) void prep_kernel(
    const float* __restrict__ partial, float* __restrict__ x) {
    const int tid = threadIdx.x;
    const int colBase = blockIdx.x * 32;
    const int kl = tid >> 5;    // 0..7
    const int cl = tid & 31;    // 0..31

    float ssum = 0.f;
    #pragma unroll 8
    for (int c = kl; c < CHUNKS; c += 8)
        ssum += partial[(size_t)c * N + colBase + cl];

    __shared__ float red[8][32];
    red[kl][cl] = ssum;
    __syncthreads();
    if (tid < 32) {
        float tot = 0.f;
        #pragma unroll
        for (int g = 0; g < 8; ++g) tot += red[g][tid];
        x[colBase + tid] = 1.0f / (tot + EPS);
    }
}

// ---- final: out[i][j] = u[i] * exp(s[i][j]) * m[i][j] * v[j] (fp32 exact K) ----
__global__ __launch_bounds__(256) void final_kernel(
    const float* __restrict__ s, const float* __restrict__ m,
    const float* __restrict__ u, const float* __restrict__ v,
    float* __restrict__ out) {
    const int row = blockIdx.x;
    const float ur = u[row];
    const int tid = threadIdx.x;
    #pragma unroll
    for (int sweep = 0; sweep < 8; ++sweep) {
        const int col = sweep * 1024 + tid * 4;
        const size_t idx = (size_t)row * N + col;
        const float4 s4 = *(const float4*)(s + idx);
        const float4 m4 = *(const float4*)(m + idx);
        const float4 v4 = *(const float4*)(v + col);
        float4 o;
        o.x = ur * __expf(s4.x) * m4.x * v4.x;
        o.y = ur * __expf(s4.y) * m4.y * v4.y;
        o.z = ur * __expf(s4.z) * m4.z * v4.z;
        o.w = ur * __expf(s4.w) * m4.w * v4.w;
        *(float4*)(out + idx) = o;
    }
}

extern "C" void kernel_launch(void* const* d_in, const int* in_sizes, int n_in,
                              void* d_out, int out_size, void* d_ws, size_t ws_size,
                              hipStream_t stream) {
    const float* eta = (const float*)d_in[0];
    const float* s = eta;                       // eta_result[0]: scores
    const float* m = eta + (size_t)N * N;       // eta_result[1]: mask
    float* out = (float*)d_out;

    // workspace: K bf16 (128 MiB) | partial fp32 [CHUNKS][N] (16 MiB) | x | u
    unsigned short* K = (unsigned short*)d_ws;
    float* partial = (float*)(K + (size_t)N * N);
    float* x = partial + (size_t)CHUNKS * N;
    float* u = x + N;

    init_x_kernel<<<N / 256, 256, 0, stream>>>(x);
    build_K_kernel<<<(int)(((size_t)N * N) / 2048), 256, 0, stream>>>(s, m, K);
    for (int it = 0; it < 20; ++it) {
        // one pass over K: u = 1/(K x + eps)  AND  partial rows of K^T u
        fused_iter_kernel<<<CHUNKS, 256, 0, stream>>>(K, x, u, partial);
        // x = 1/(sum partials + eps)  (the next v vector)
        prep_kernel<<<N / 32, 256, 0, stream>>>(partial, x);
    }
    final_kernel<<<N, 256, 0, stream>>>(s, m, u, x, out);
}